// Round 5
// baseline (722.778 us; speedup 1.0000x reference)
//
#include <hip/hip_runtime.h>
#include <cstdint>

// Problem constants
#define BB 16
#define NN 512
#define CC 768
#define HH 12
#define DD 64
#define HID 3072

typedef __bf16 bf16;
typedef __bf16 bf16x4 __attribute__((ext_vector_type(4)));
typedef __bf16 bf16x8 __attribute__((ext_vector_type(8)));
typedef float f32x4 __attribute__((ext_vector_type(4)));

__device__ __forceinline__ f32x4 mfma16(bf16x8 a, bf16x8 b, f32x4 c) {
    return __builtin_amdgcn_mfma_f32_16x16x32_bf16(a, b, c, 0, 0, 0);
}

// async global->LDS, 16B per lane. LDS dest = wave-uniform base + lane*16.
__device__ __forceinline__ void g2l16(const bf16* g, bf16* l) {
    __builtin_amdgcn_global_load_lds(
        (const __attribute__((address_space(1))) void*)g,
        (__attribute__((address_space(3))) void*)l, 16, 0, 0);
}

// ---------------- LayerNorm: one wave per token over C=768 (fp32 in, bf16 out) ----------------
__global__ __launch_bounds__(256) void ln_kernel(
    const float* __restrict__ in, bf16* __restrict__ out,
    const float* __restrict__ g, const float* __restrict__ bt,
    int ntok, int base)
{
    int w = threadIdx.x >> 6, lane = threadIdx.x & 63;
    int t = blockIdx.x * 4 + w;
    if (t >= ntok) return;
    long row = (base < 0) ? t : ((long)(t >> 8) * NN + (t & 255) + base);
    const float* xr = in + row * CC;
    float vals[12];
    float s = 0.f, sq = 0.f;
    #pragma unroll
    for (int i = 0; i < 3; i++) {
        int off = lane * 4 + i * 256;
        f32x4 v4 = *(const f32x4*)&xr[off];
        #pragma unroll
        for (int e = 0; e < 4; e++) {
            vals[i * 4 + e] = v4[e];
            s += v4[e]; sq += v4[e] * v4[e];
        }
    }
    #pragma unroll
    for (int m = 1; m < 64; m <<= 1) { s += __shfl_xor(s, m); sq += __shfl_xor(sq, m); }
    float mean = s * (1.f / 768.f);
    float var  = sq * (1.f / 768.f) - mean * mean;
    float rstd = rsqrtf(var + 1e-5f);
    bf16* orow = out + (long)t * CC;   // compact output
    #pragma unroll
    for (int i = 0; i < 3; i++) {
        int off = lane * 4 + i * 256;
        bf16x4 ov;
        #pragma unroll
        for (int e = 0; e < 4; e++) {
            float f = (vals[i * 4 + e] - mean) * rstd * g[off + e] + bt[off + e];
            ov[e] = (bf16)f;
        }
        *(bf16x4*)&orow[off] = ov;
    }
}

// ------- 128x128 MFMA GEMM: C = A[M,K](bf16) @ Bt[N,K](fp32)^T, fused epilogues -------
enum { MODE_QKV = 0, MODE_PROJ = 1, MODE_GELU = 2, MODE_OUT = 3 };

template<int MODE, int K>
__global__ __launch_bounds__(256) void gemm_bt(
    const bf16* __restrict__ A, const float* __restrict__ Btf,
    const float* __restrict__ cbias, const float* residf,   // fp32 residual (may alias outf)
    const float* __restrict__ gamma,
    bf16* __restrict__ outb0, bf16* __restrict__ outb1, bf16* __restrict__ outb2,
    float* outf, int rowbase)
{
    __shared__ bf16 lsA[128 * 32];
    __shared__ bf16 lsB[128 * 32];
    int tid = threadIdx.x;
    int lane = tid & 63, w = tid >> 6;
    int wm = w & 1, wn = w >> 1;
    long m0 = (long)blockIdx.y * 128;
    long n0 = (long)blockIdx.x * 128;
    f32x4 acc[4][4] = {};
    const bf16* Ab = A + m0 * K;
    const float* Bb = Btf + n0 * K;
    int r0 = tid >> 2, kg0 = (tid & 3) * 8;   // A-stage: 8 bf16 = 16B per lane
    int r1 = tid >> 1, kh = (tid & 1) * 16;   // B-stage: 16 fp32 per thread
    int la = lane & 15, hk = (lane >> 4) * 8;

    for (int k0 = 0; k0 < K; k0 += 32) {
        g2l16(Ab + (long)r0 * K + k0 + kg0,        lsA + tid * 8);
        g2l16(Ab + (long)(r0 + 64) * K + k0 + kg0, lsA + (tid + 256) * 8);
        {
            const float* src = Bb + (long)r1 * K + k0 + kh;
            f32x4 w0 = *(const f32x4*)(src);
            f32x4 w1 = *(const f32x4*)(src + 4);
            f32x4 w2 = *(const f32x4*)(src + 8);
            f32x4 w3 = *(const f32x4*)(src + 12);
            bf16x8 p0, p1;
            #pragma unroll
            for (int e = 0; e < 4; e++) {
                p0[e] = (bf16)w0[e]; p0[4 + e] = (bf16)w1[e];
                p1[e] = (bf16)w2[e]; p1[4 + e] = (bf16)w3[e];
            }
            *(bf16x8*)&lsB[r1 * 32 + kh]     = p0;
            *(bf16x8*)&lsB[r1 * 32 + kh + 8] = p1;
        }
        __syncthreads();
        bf16x8 af[4], bfr[4];
        #pragma unroll
        for (int mi = 0; mi < 4; mi++) af[mi]  = *(bf16x8*)&lsA[(wm * 64 + mi * 16 + la) * 32 + hk];
        #pragma unroll
        for (int ni = 0; ni < 4; ni++) bfr[ni] = *(bf16x8*)&lsB[(wn * 64 + ni * 16 + la) * 32 + hk];
        #pragma unroll
        for (int mi = 0; mi < 4; mi++)
            #pragma unroll
            for (int ni = 0; ni < 4; ni++)
                acc[mi][ni] = mfma16(af[mi], bfr[ni], acc[mi][ni]);
        __syncthreads();
    }

    int q4 = (lane >> 4) * 4;
    #pragma unroll
    for (int mi = 0; mi < 4; mi++) {
        #pragma unroll
        for (int ni = 0; ni < 4; ni++) {
            long rb = m0 + wm * 64 + mi * 16 + q4;
            long c  = n0 + wn * 64 + ni * 16 + la;
            #pragma unroll
            for (int i = 0; i < 4; i++) {
                long r = rb + i;
                float v = acc[mi][ni][i];
                if (MODE == MODE_QKV) {
                    int oc = (int)c;
                    int s = oc / CC, rem = oc % CC;
                    int hh = rem >> 6, d = rem & 63;
                    long b = r >> 9, n = r & 511;
                    long dst = (((b * HH + hh) << 9) + n) * 64 + d;
                    if (s == 0)      outb0[dst] = (bf16)(v * 0.125f);
                    else if (s == 1) outb1[dst] = (bf16)v;
                    else             outb2[dst] = (bf16)v;
                } else if (MODE == MODE_PROJ) {
                    float val = v + cbias[c];
                    long idx = r * CC + c;
                    outf[idx] = residf[idx] + gamma[c] * val;   // x1 fp32
                } else if (MODE == MODE_GELU) {
                    float val = v + cbias[c];
                    float gl = 0.5f * val * (1.f + erff(val * 0.70710678118f));
                    outb0[r * (long)HID + c] = (bf16)gl;
                } else {  // MODE_OUT (residf aliases outf: per-thread read-then-write, same idx)
                    float val = v + cbias[c];
                    long grow = (r >> 8) * NN + (r & 255) + rowbase;
                    long idx = grow * CC + c;
                    float res = residf[idx];
                    outf[idx] = res + gamma[c] * val;
                }
            }
        }
    }
}

// ---------------- Flash attention: block = (b,h, 64 Q rows) ----------------
__global__ __launch_bounds__(256) void attn_kernel(
    const bf16* __restrict__ q, const bf16* __restrict__ k, const bf16* __restrict__ v,
    const int* __restrict__ rpi, const float* __restrict__ table, bf16* __restrict__ o)
{
    __shared__ bf16 lsK[32 * 64];
    __shared__ bf16 lsVT[64 * 32];
    __shared__ bf16 lsP[4][16 * 32];
    int tid = threadIdx.x, lane = tid & 63, w = tid >> 6;
    int qt = blockIdx.x & 7;
    int bh = blockIdx.x >> 3;
    int h = bh % HH, b = bh / HH;
    long base = (long)bh * NN * DD;
    int la = lane & 15, hi = lane >> 4;
    int qr0 = qt * 64 + w * 16;

    bf16x8 qf0 = *(const bf16x8*)&q[base + (qr0 + la) * 64 + hi * 8];
    bf16x8 qf1 = *(const bf16x8*)&q[base + (qr0 + la) * 64 + 32 + hi * 8];
    f32x4 of[4] = {};
    float m[4], l[4];
    #pragma unroll
    for (int i = 0; i < 4; i++) { m[i] = -1e30f; l[i] = 0.f; }

    int jr = tid >> 3, dg = (tid & 7) * 8;
    for (int ch = 0; ch < 16; ch++) {
        int j0 = ch * 32;
        *(bf16x8*)&lsK[jr * 64 + dg] = *(const bf16x8*)&k[base + (j0 + jr) * 64 + dg];
        bf16x8 vvv = *(const bf16x8*)&v[base + (j0 + jr) * 64 + dg];
        #pragma unroll
        for (int e = 0; e < 8; e++) lsVT[(dg + e) * 32 + jr] = vvv[e];
        __syncthreads();

        f32x4 s0 = {0.f, 0.f, 0.f, 0.f}, s1 = {0.f, 0.f, 0.f, 0.f};
        {
            bf16x8 kf0 = *(bf16x8*)&lsK[la * 64 + hi * 8];
            bf16x8 kf1 = *(bf16x8*)&lsK[la * 64 + 32 + hi * 8];
            s0 = mfma16(qf0, kf0, s0);
            s0 = mfma16(qf1, kf1, s0);
            bf16x8 kf2 = *(bf16x8*)&lsK[(16 + la) * 64 + hi * 8];
            bf16x8 kf3 = *(bf16x8*)&lsK[(16 + la) * 64 + 32 + hi * 8];
            s1 = mfma16(qf0, kf2, s1);
            s1 = mfma16(qf1, kf3, s1);
        }
        #pragma unroll
        for (int i = 0; i < 4; i++) {
            int qrow = qr0 + hi * 4 + i;
            int r0i = rpi[qrow * NN + j0 + la];
            int r1i = rpi[qrow * NN + j0 + la + 16];
            s0[i] += table[r0i * HH + h];
            s1[i] += table[r1i * HH + h];
        }
        float alpha[4];
        #pragma unroll
        for (int i = 0; i < 4; i++) {
            float mx = fmaxf(s0[i], s1[i]);
            #pragma unroll
            for (int msk = 1; msk < 16; msk <<= 1) mx = fmaxf(mx, __shfl_xor(mx, msk));
            float mn = fmaxf(m[i], mx);
            alpha[i] = __expf(m[i] - mn);
            m[i] = mn;
            s0[i] = __expf(s0[i] - mn);
            s1[i] = __expf(s1[i] - mn);
            float rs = s0[i] + s1[i];
            #pragma unroll
            for (int msk = 1; msk < 16; msk <<= 1) rs += __shfl_xor(rs, msk);
            l[i] = l[i] * alpha[i] + rs;
        }
        #pragma unroll
        for (int t = 0; t < 4; t++)
            #pragma unroll
            for (int i = 0; i < 4; i++) of[t][i] *= alpha[i];
        #pragma unroll
        for (int i = 0; i < 4; i++) {
            lsP[w][(hi * 4 + i) * 32 + la]      = (bf16)s0[i];
            lsP[w][(hi * 4 + i) * 32 + 16 + la] = (bf16)s1[i];
        }
        __syncthreads();
        bf16x8 pf = *(bf16x8*)&lsP[w][la * 32 + hi * 8];
        #pragma unroll
        for (int t = 0; t < 4; t++) {
            bf16x8 vf = *(bf16x8*)&lsVT[(t * 16 + la) * 32 + hi * 8];
            of[t] = mfma16(pf, vf, of[t]);
        }
        __syncthreads();
    }
    #pragma unroll
    for (int t = 0; t < 4; t++) {
        #pragma unroll
        for (int i = 0; i < 4; i++) {
            long row = (long)b * NN + qr0 + hi * 4 + i;
            o[row * CC + h * 64 + t * 16 + la] = (bf16)(of[t][i] / l[i]);
        }
    }
}

extern "C" void kernel_launch(void* const* d_in, const int* in_sizes, int n_in,
                              void* d_out, int out_size, void* d_ws, size_t ws_size,
                              hipStream_t stream)
{
    const float* x     = (const float*)d_in[0];
    const int*   rpi   = (const int*)d_in[2];
    const float* Wqkv  = (const float*)d_in[3];
    const float* Wproj = (const float*)d_in[4];
    const float* bproj = (const float*)d_in[5];
    const float* rtab  = (const float*)d_in[6];
    const float* ln1g  = (const float*)d_in[7];
    const float* ln1b  = (const float*)d_in[8];
    const float* g1    = (const float*)d_in[9];
    const float* g2    = (const float*)d_in[10];
    const float* ln2tg = (const float*)d_in[11];
    const float* ln2tb = (const float*)d_in[12];
    const float* f1tW  = (const float*)d_in[13];
    const float* f1tb  = (const float*)d_in[14];
    const float* f2tW  = (const float*)d_in[15];
    const float* f2tb  = (const float*)d_in[16];
    const float* ln2fg = (const float*)d_in[17];
    const float* ln2fb = (const float*)d_in[18];
    const float* f1fW  = (const float*)d_in[19];
    const float* f1fb  = (const float*)d_in[20];
    const float* f2fW  = (const float*)d_in[21];
    const float* f2fb  = (const float*)d_in[22];
    float* out = (float*)d_out;   // OUTPUT IS FP32 (reference returns float32)

    // ws: 4 regions x 12.58MB bf16 = 50.33MB.
    //  rA: q -> h2 (MLP LN out)   rB: k -> hg lo   rC: v -> hg hi   rD: o
    // d_out (25.17MB fp32) doubles as: h (bf16, first 12.58MB) then x1 (fp32, full).
    char* ws = (char*)d_ws;
    const long TOKC = (long)BB * NN * CC;   // 6291456
    bf16* rA = (bf16*)ws;
    bf16* rB = rA + TOKC;
    bf16* rC = rB + TOKC;
    bf16* rD = rC + TOKC;

    bf16 *qb = rA, *kb = rB, *vb = rC, *o = rD;
    bf16  *h  = (bf16*)d_out;   // dead once QKV done (PROJ then overwrites with x1)
    float *x1 = out;            // fp32 residual stream in d_out
    bf16  *h2 = rA;             // q dead after attention
    bf16  *hg = rB;             // spans rB+rC (k,v dead after attention)

    // 1. LN1: fp32 x -> bf16 h (in d_out)
    ln_kernel<<<2048, 256, 0, stream>>>(x, h, ln1g, ln1b, 8192, -1);
    // 2. QKV projection (scatter epilogue, q scaled by 0.125)
    {
        dim3 g(2304 / 128, 8192 / 128);
        gemm_bt<MODE_QKV, 768><<<g, 256, 0, stream>>>(h, Wqkv, nullptr, nullptr, nullptr, qb, kb, vb, nullptr, 0);
    }
    // 3. attention (reads rA,rB,rC; writes o=rD)
    attn_kernel<<<BB * HH * 8, 256, 0, stream>>>(qb, kb, vb, rpi, rtab, o);
    // 4. proj + residual -> x1 (fp32, overwrites all of d_out)
    {
        dim3 g(768 / 128, 8192 / 128);
        gemm_bt<MODE_PROJ, 768><<<g, 256, 0, stream>>>(o, Wproj, bproj, x, g1, nullptr, nullptr, nullptr, x1, 0);
    }
    // 5. MLP t-half (rows n in [0,256))
    ln_kernel<<<1024, 256, 0, stream>>>(x1, h2, ln2tg, ln2tb, 4096, 0);
    {
        dim3 ga(3072 / 128, 4096 / 128);
        gemm_bt<MODE_GELU, 768><<<ga, 256, 0, stream>>>(h2, f1tW, f1tb, nullptr, nullptr, hg, nullptr, nullptr, nullptr, 0);
        dim3 gb(768 / 128, 4096 / 128);
        gemm_bt<MODE_OUT, 3072><<<gb, 256, 0, stream>>>(hg, f2tW, f2tb, x1, g2, nullptr, nullptr, nullptr, out, 0);
    }
    // 6. MLP f-half (rows n in [256,512))
    ln_kernel<<<1024, 256, 0, stream>>>(x1, h2, ln2fg, ln2fb, 4096, 256);
    {
        dim3 ga(3072 / 128, 4096 / 128);
        gemm_bt<MODE_GELU, 768><<<ga, 256, 0, stream>>>(h2, f1fW, f1fb, nullptr, nullptr, hg, nullptr, nullptr, nullptr, 0);
        dim3 gb(768 / 128, 4096 / 128);
        gemm_bt<MODE_OUT, 3072><<<gb, 256, 0, stream>>>(hg, f2fW, f2fb, x1, g2, nullptr, nullptr, nullptr, out, 256);
    }
}

// Round 6
// 594.800 us; speedup vs baseline: 1.2152x; 1.2152x over previous
//
#include <hip/hip_runtime.h>
#include <cstdint>

// Problem constants
#define BB 16
#define NN 512
#define CC 768
#define HH 12
#define DD 64
#define HID 3072

typedef __bf16 bf16;
typedef __bf16 bf16x4 __attribute__((ext_vector_type(4)));
typedef __bf16 bf16x8 __attribute__((ext_vector_type(8)));
typedef float f32x4 __attribute__((ext_vector_type(4)));

__device__ __forceinline__ f32x4 mfma16(bf16x8 a, bf16x8 b, f32x4 c) {
    return __builtin_amdgcn_mfma_f32_16x16x32_bf16(a, b, c, 0, 0, 0);
}

__device__ __forceinline__ void g2l16(const bf16* g, bf16* l) {
    __builtin_amdgcn_global_load_lds(
        (const __attribute__((address_space(1))) void*)g,
        (__attribute__((address_space(3))) void*)l, 16, 0, 0);
}

// ---------------- LayerNorm (+optional x1 += g2*b2 writeback for MLP bias pre-add) ----------------
__global__ __launch_bounds__(256) void ln_kernel(
    const float* __restrict__ in, bf16* __restrict__ out,
    const float* __restrict__ g, const float* __restrict__ bt,
    const float* __restrict__ g2, const float* __restrict__ b2, float* wb,
    int ntok, int base)
{
    int w = threadIdx.x >> 6, lane = threadIdx.x & 63;
    int t = blockIdx.x * 4 + w;
    if (t >= ntok) return;
    long row = (base < 0) ? t : ((long)(t >> 8) * NN + (t & 255) + base);
    const float* xr = in + row * CC;
    float vals[12];
    float s = 0.f, sq = 0.f;
    #pragma unroll
    for (int i = 0; i < 3; i++) {
        int off = lane * 4 + i * 256;
        f32x4 v4 = *(const f32x4*)&xr[off];
        #pragma unroll
        for (int e = 0; e < 4; e++) {
            vals[i * 4 + e] = v4[e];
            s += v4[e]; sq += v4[e] * v4[e];
        }
    }
    #pragma unroll
    for (int m = 1; m < 64; m <<= 1) { s += __shfl_xor(s, m); sq += __shfl_xor(sq, m); }
    float mean = s * (1.f / 768.f);
    float var  = sq * (1.f / 768.f) - mean * mean;
    float rstd = rsqrtf(var + 1e-5f);
    bf16* orow = out + (long)t * CC;
    #pragma unroll
    for (int i = 0; i < 3; i++) {
        int off = lane * 4 + i * 256;
        bf16x4 ov;
        f32x4 wv;
        #pragma unroll
        for (int e = 0; e < 4; e++) {
            float f = (vals[i * 4 + e] - mean) * rstd * g[off + e] + bt[off + e];
            ov[e] = (bf16)f;
            if (wb) wv[e] = vals[i * 4 + e] + g2[off + e] * b2[off + e];
        }
        *(bf16x4*)&orow[off] = ov;
        if (wb) *(f32x4*)&wb[row * CC + off] = wv;
    }
}

// ---------------- bias precompute: bb[h][i][j] = table[rpi[i*512+j]*12 + h] ----------------
__global__ __launch_bounds__(256) void bias_kernel(
    const int* __restrict__ rpi, const float* __restrict__ table, bf16* __restrict__ bb)
{
    int idx = blockIdx.x * 256 + threadIdx.x;   // i*512+j
    int r = rpi[idx];
    #pragma unroll
    for (int h = 0; h < HH; h++) bb[h * (NN * NN) + idx] = (bf16)table[r * HH + h];
}

// ------- 128x128 MFMA GEMM, double-buffered pipeline: C = A[M,K](bf16) @ Bt[N,K](fp32)^T -------
enum { MODE_QKV = 0, MODE_PROJ = 1, MODE_GELU = 2, MODE_OUT = 3 };

template<int MODE, int K, int KCHUNK>
__global__ __launch_bounds__(256) void gemm_bt(
    const bf16* __restrict__ A, const float* __restrict__ Btf,
    const float* __restrict__ cbias, const float* residf,
    const float* __restrict__ gamma,
    bf16* __restrict__ outb0, bf16* __restrict__ outb1, bf16* __restrict__ outb2,
    float* outf, int rowbase)
{
    __shared__ bf16 lsA[2][128 * 32];
    __shared__ bf16 lsB[2][128 * 32];
    int tid = threadIdx.x;
    int lane = tid & 63, w = tid >> 6;
    int wm = w & 1, wn = w >> 1;
    long m0 = (long)blockIdx.y * 128;
    long n0 = (long)blockIdx.x * 128;
    long kb = (long)blockIdx.z * KCHUNK;
    f32x4 acc[4][4] = {};
    const bf16* Ab = A + m0 * K + kb;
    const float* Bb = Btf + n0 * K + kb;
    int r0 = tid >> 2, kg0 = (tid & 3) * 8;   // A-stage: 8 bf16 = 16B per lane
    int r1 = tid >> 1, kh = (tid & 1) * 16;   // B-stage: 16 fp32 per thread
    int la = lane & 15, hk = (lane >> 4) * 8;

    // prologue: stage k0=0 into buffer 0
    g2l16(Ab + (long)r0 * K + kg0,        lsA[0] + tid * 8);
    g2l16(Ab + (long)(r0 + 64) * K + kg0, lsA[0] + (tid + 256) * 8);
    {
        const float* src = Bb + (long)r1 * K + kh;
        f32x4 w0 = *(const f32x4*)(src);
        f32x4 w1 = *(const f32x4*)(src + 4);
        f32x4 w2 = *(const f32x4*)(src + 8);
        f32x4 w3 = *(const f32x4*)(src + 12);
        bf16x8 p0, p1;
        #pragma unroll
        for (int e = 0; e < 4; e++) {
            p0[e] = (bf16)w0[e]; p0[4 + e] = (bf16)w1[e];
            p1[e] = (bf16)w2[e]; p1[4 + e] = (bf16)w3[e];
        }
        *(bf16x8*)&lsB[0][r1 * 32 + kh]     = p0;
        *(bf16x8*)&lsB[0][r1 * 32 + kh + 8] = p1;
    }
    __syncthreads();

    int p = 0;
    for (int k0 = 0; k0 < KCHUNK; k0 += 32) {
        bool pre = (k0 + 32 < KCHUNK);
        f32x4 n0r = {}, n1r = {}, n2r = {}, n3r = {};
        if (pre) {
            g2l16(Ab + (long)r0 * K + (k0 + 32) + kg0,        lsA[p ^ 1] + tid * 8);
            g2l16(Ab + (long)(r0 + 64) * K + (k0 + 32) + kg0, lsA[p ^ 1] + (tid + 256) * 8);
            const float* src = Bb + (long)r1 * K + (k0 + 32) + kh;
            n0r = *(const f32x4*)(src);
            n1r = *(const f32x4*)(src + 4);
            n2r = *(const f32x4*)(src + 8);
            n3r = *(const f32x4*)(src + 12);
        }
        bf16x8 af[4], bfr[4];
        #pragma unroll
        for (int mi = 0; mi < 4; mi++) af[mi]  = *(bf16x8*)&lsA[p][(wm * 64 + mi * 16 + la) * 32 + hk];
        #pragma unroll
        for (int ni = 0; ni < 4; ni++) bfr[ni] = *(bf16x8*)&lsB[p][(wn * 64 + ni * 16 + la) * 32 + hk];
        #pragma unroll
        for (int mi = 0; mi < 4; mi++)
            #pragma unroll
            for (int ni = 0; ni < 4; ni++)
                acc[mi][ni] = mfma16(af[mi], bfr[ni], acc[mi][ni]);
        if (pre) {
            bf16x8 p0, p1;
            #pragma unroll
            for (int e = 0; e < 4; e++) {
                p0[e] = (bf16)n0r[e]; p0[4 + e] = (bf16)n1r[e];
                p1[e] = (bf16)n2r[e]; p1[4 + e] = (bf16)n3r[e];
            }
            *(bf16x8*)&lsB[p ^ 1][r1 * 32 + kh]     = p0;
            *(bf16x8*)&lsB[p ^ 1][r1 * 32 + kh + 8] = p1;
        }
        __syncthreads();
        p ^= 1;
    }

    int q4 = (lane >> 4) * 4;
    #pragma unroll
    for (int mi = 0; mi < 4; mi++) {
        #pragma unroll
        for (int ni = 0; ni < 4; ni++) {
            long rb = m0 + wm * 64 + mi * 16 + q4;
            long c  = n0 + wn * 64 + ni * 16 + la;
            #pragma unroll
            for (int i = 0; i < 4; i++) {
                long r = rb + i;
                float v = acc[mi][ni][i];
                if (MODE == MODE_QKV) {
                    int oc = (int)c;
                    int s = oc / CC, rem = oc % CC;
                    int hh = rem >> 6, d = rem & 63;
                    long b = r >> 9, n = r & 511;
                    long dst = (((b * HH + hh) << 9) + n) * 64 + d;
                    if (s == 0)      outb0[dst] = (bf16)(v * 0.125f);
                    else if (s == 1) outb1[dst] = (bf16)v;
                    else             outb2[dst] = (bf16)v;
                } else if (MODE == MODE_PROJ) {
                    float val = v + cbias[c];
                    long idx = r * CC + c;
                    outf[idx] = residf[idx] + gamma[c] * val;
                } else if (MODE == MODE_GELU) {
                    float val = v + cbias[c];
                    float gl = 0.5f * val * (1.f + erff(val * 0.70710678118f));
                    outb0[r * (long)HID + c] = (bf16)gl;
                } else {  // MODE_OUT: bias pre-added by ln2 writeback; split-K atomic accumulate
                    long grow = (r >> 8) * NN + (r & 255) + rowbase;
                    atomicAdd(outf + grow * CC + c, gamma[c] * v);
                }
            }
        }
    }
}

// ---------------- Flash attention: block = (b,h, 64 Q rows) ----------------
// lsK padded stride 72; lsVT xor-swizzled j-blocks; lsP stride 40.
__global__ __launch_bounds__(256) void attn_kernel(
    const bf16* __restrict__ q, const bf16* __restrict__ k, const bf16* __restrict__ v,
    const bf16* __restrict__ bb, bf16* __restrict__ o)
{
    __shared__ bf16 lsK[32 * 72];
    __shared__ bf16 lsVT[64 * 32];
    __shared__ bf16 lsP[4][16 * 40];
    int tid = threadIdx.x, lane = tid & 63, w = tid >> 6;
    int qt = blockIdx.x & 7;
    int bh = blockIdx.x >> 3;
    int h = bh % HH, b = bh / HH;
    long base = (long)bh * NN * DD;
    int la = lane & 15, hi = lane >> 4;
    int qr0 = qt * 64 + w * 16;
    const bf16* brow = bb + (long)h * NN * NN;

    bf16x8 qf0 = *(const bf16x8*)&q[base + (qr0 + la) * 64 + hi * 8];
    bf16x8 qf1 = *(const bf16x8*)&q[base + (qr0 + la) * 64 + 32 + hi * 8];
    f32x4 of[4] = {};
    float m[4], l[4];
    #pragma unroll
    for (int i = 0; i < 4; i++) { m[i] = -1e30f; l[i] = 0.f; }

    int jr = tid >> 3, dgi = tid & 7, dg = dgi * 8;
    int vjb = (((jr >> 3) ^ dgi) & 3) * 8 + (jr & 7);   // swizzled j-slot for V^T stores
    for (int ch = 0; ch < 16; ch++) {
        int j0 = ch * 32;
        *(bf16x8*)&lsK[jr * 72 + dg] = *(const bf16x8*)&k[base + (j0 + jr) * 64 + dg];
        bf16x8 vvv = *(const bf16x8*)&v[base + (j0 + jr) * 64 + dg];
        #pragma unroll
        for (int e = 0; e < 8; e++) lsVT[(dg + e) * 32 + vjb] = vvv[e];
        __syncthreads();

        f32x4 s0 = {0.f, 0.f, 0.f, 0.f}, s1 = {0.f, 0.f, 0.f, 0.f};
        {
            bf16x8 kf0 = *(bf16x8*)&lsK[la * 72 + hi * 8];
            bf16x8 kf1 = *(bf16x8*)&lsK[la * 72 + 32 + hi * 8];
            s0 = mfma16(qf0, kf0, s0);
            s0 = mfma16(qf1, kf1, s0);
            bf16x8 kf2 = *(bf16x8*)&lsK[(16 + la) * 72 + hi * 8];
            bf16x8 kf3 = *(bf16x8*)&lsK[(16 + la) * 72 + 32 + hi * 8];
            s1 = mfma16(qf0, kf2, s1);
            s1 = mfma16(qf1, kf3, s1);
        }
        // + relative position bias (contiguous bf16 table)
        #pragma unroll
        for (int i = 0; i < 4; i++) {
            long bidx = (long)(qr0 + hi * 4 + i) * NN + j0 + la;
            s0[i] += (float)brow[bidx];
            s1[i] += (float)brow[bidx + 16];
        }
        float alpha[4];
        #pragma unroll
        for (int i = 0; i < 4; i++) {
            float mx = fmaxf(s0[i], s1[i]);
            #pragma unroll
            for (int msk = 1; msk < 16; msk <<= 1) mx = fmaxf(mx, __shfl_xor(mx, msk));
            float mn = fmaxf(m[i], mx);
            alpha[i] = __expf(m[i] - mn);
            m[i] = mn;
            s0[i] = __expf(s0[i] - mn);
            s1[i] = __expf(s1[i] - mn);
            float rs = s0[i] + s1[i];
            #pragma unroll
            for (int msk = 1; msk < 16; msk <<= 1) rs += __shfl_xor(rs, msk);
            l[i] = l[i] * alpha[i] + rs;
        }
        #pragma unroll
        for (int t = 0; t < 4; t++)
            #pragma unroll
            for (int i = 0; i < 4; i++) of[t][i] *= alpha[i];
        #pragma unroll
        for (int i = 0; i < 4; i++) {
            lsP[w][(hi * 4 + i) * 40 + la]      = (bf16)s0[i];
            lsP[w][(hi * 4 + i) * 40 + 16 + la] = (bf16)s1[i];
        }
        __syncthreads();
        bf16x8 pf = *(bf16x8*)&lsP[w][la * 40 + hi * 8];
        #pragma unroll
        for (int t = 0; t < 4; t++) {
            int drow = t * 16 + la;
            int jb = (hi ^ ((drow >> 3) & 3)) * 8;
            bf16x8 vf = *(bf16x8*)&lsVT[drow * 32 + jb];
            of[t] = mfma16(pf, vf, of[t]);
        }
        __syncthreads();
    }
    #pragma unroll
    for (int t = 0; t < 4; t++) {
        #pragma unroll
        for (int i = 0; i < 4; i++) {
            long row = (long)b * NN + qr0 + hi * 4 + i;
            o[row * CC + h * 64 + t * 16 + la] = (bf16)(of[t][i] / l[i]);
        }
    }
}

extern "C" void kernel_launch(void* const* d_in, const int* in_sizes, int n_in,
                              void* d_out, int out_size, void* d_ws, size_t ws_size,
                              hipStream_t stream)
{
    const float* x     = (const float*)d_in[0];
    const int*   rpi   = (const int*)d_in[2];
    const float* Wqkv  = (const float*)d_in[3];
    const float* Wproj = (const float*)d_in[4];
    const float* bproj = (const float*)d_in[5];
    const float* rtab  = (const float*)d_in[6];
    const float* ln1g  = (const float*)d_in[7];
    const float* ln1b  = (const float*)d_in[8];
    const float* g1    = (const float*)d_in[9];
    const float* g2    = (const float*)d_in[10];
    const float* ln2tg = (const float*)d_in[11];
    const float* ln2tb = (const float*)d_in[12];
    const float* f1tW  = (const float*)d_in[13];
    const float* f1tb  = (const float*)d_in[14];
    const float* f2tW  = (const float*)d_in[15];
    const float* f2tb  = (const float*)d_in[16];
    const float* ln2fg = (const float*)d_in[17];
    const float* ln2fb = (const float*)d_in[18];
    const float* f1fW  = (const float*)d_in[19];
    const float* f1fb  = (const float*)d_in[20];
    const float* f2fW  = (const float*)d_in[21];
    const float* f2fb  = (const float*)d_in[22];
    float* out = (float*)d_out;

    // ws: 4 regions x 12.58MB bf16 = 50.33MB.
    //  rA: q -> h2   rB: k -> hg lo   rC: v -> hg hi   rD: o
    // d_out: h (bf16 LN1 out) -> bias table (bf16, after QKV) -> x1 (fp32, after attn)
    char* ws = (char*)d_ws;
    const long TOKC = (long)BB * NN * CC;
    bf16* rA = (bf16*)ws;
    bf16* rB = rA + TOKC;
    bf16* rC = rB + TOKC;
    bf16* rD = rC + TOKC;

    bf16 *qb = rA, *kb = rB, *vb = rC, *o = rD;
    bf16  *h   = (bf16*)d_out;
    bf16  *bbt = (bf16*)d_out;   // bias table overwrites h after QKV
    float *x1  = out;
    bf16  *h2  = rA;
    bf16  *hg  = rB;             // spans rB+rC

    // 1. LN1
    ln_kernel<<<2048, 256, 0, stream>>>(x, h, ln1g, ln1b, nullptr, nullptr, nullptr, 8192, -1);
    // 2. QKV projection
    {
        dim3 g(2304 / 128, 8192 / 128, 1);
        gemm_bt<MODE_QKV, 768, 768><<<g, 256, 0, stream>>>(h, Wqkv, nullptr, nullptr, nullptr, qb, kb, vb, nullptr, 0);
    }
    // 3. bias table precompute (h is dead now)
    bias_kernel<<<1024, 256, 0, stream>>>(rpi, rtab, bbt);
    // 4. attention
    attn_kernel<<<BB * HH * 8, 256, 0, stream>>>(qb, kb, vb, bbt, o);
    // 5. proj + residual -> x1 (overwrites d_out)
    {
        dim3 g(768 / 128, 8192 / 128, 1);
        gemm_bt<MODE_PROJ, 768, 768><<<g, 256, 0, stream>>>(o, Wproj, bproj, x, g1, nullptr, nullptr, nullptr, x1, 0);
    }
    // 6. MLP t-half: LN2 (+ x1 += g2*fc2b), GELU, OUT(split-K=2, atomic)
    ln_kernel<<<1024, 256, 0, stream>>>(x1, h2, ln2tg, ln2tb, g2, f2tb, x1, 4096, 0);
    {
        dim3 ga(3072 / 128, 4096 / 128, 1);
        gemm_bt<MODE_GELU, 768, 768><<<ga, 256, 0, stream>>>(h2, f1tW, f1tb, nullptr, nullptr, hg, nullptr, nullptr, nullptr, 0);
        dim3 gb(768 / 128, 4096 / 128, 2);
        gemm_bt<MODE_OUT, 3072, 1536><<<gb, 256, 0, stream>>>(hg, f2tW, nullptr, nullptr, g2, nullptr, nullptr, nullptr, out, 0);
    }
    // 7. MLP f-half
    ln_kernel<<<1024, 256, 0, stream>>>(x1, h2, ln2fg, ln2fb, g2, f2fb, x1, 4096, 256);
    {
        dim3 ga(3072 / 128, 4096 / 128, 1);
        gemm_bt<MODE_GELU, 768, 768><<<ga, 256, 0, stream>>>(h2, f1fW, f1fb, nullptr, nullptr, hg, nullptr, nullptr, nullptr, 0);
        dim3 gb(768 / 128, 4096 / 128, 2);
        gemm_bt<MODE_OUT, 3072, 1536><<<gb, 256, 0, stream>>>(hg, f2fW, nullptr, nullptr, g2, nullptr, nullptr, nullptr, out, 256);
    }
}

// Round 7
// 519.098 us; speedup vs baseline: 1.3924x; 1.1458x over previous
//
#include <hip/hip_runtime.h>
#include <cstdint>

// Problem constants
#define BB 16
#define NN 512
#define CC 768
#define HH 12
#define DD 64
#define HID 3072

typedef __bf16 bf16;
typedef __bf16 bf16x4 __attribute__((ext_vector_type(4)));
typedef __bf16 bf16x8 __attribute__((ext_vector_type(8)));
typedef float f32x4 __attribute__((ext_vector_type(4)));

__device__ __forceinline__ f32x4 mfma16(bf16x8 a, bf16x8 b, f32x4 c) {
    return __builtin_amdgcn_mfma_f32_16x16x32_bf16(a, b, c, 0, 0, 0);
}

__device__ __forceinline__ void g2l16(const bf16* g, bf16* l) {
    __builtin_amdgcn_global_load_lds(
        (const __attribute__((address_space(1))) void*)g,
        (__attribute__((address_space(3))) void*)l, 16, 0, 0);
}

// ---------------- fp32->bf16 cast of one or two tensors into contiguous dst ----------------
__global__ __launch_bounds__(256) void cast2_kernel(
    const float* __restrict__ a, int na4, const float* __restrict__ b, bf16* __restrict__ dst)
{
    int i = blockIdx.x * 256 + threadIdx.x;   // grid sized exactly
    const float* s = (i < na4) ? a : b;
    int off = (i < na4) ? i : i - na4;
    f32x4 v = ((const f32x4*)s)[off];
    bf16x4 o;
    #pragma unroll
    for (int e = 0; e < 4; e++) o[e] = (bf16)v[e];
    ((bf16x4*)dst)[i] = o;
}

// ---------------- LN1: one wave per token ----------------
__global__ __launch_bounds__(256) void ln_kernel(
    const float* __restrict__ in, bf16* __restrict__ out,
    const float* __restrict__ g, const float* __restrict__ bt)
{
    int w = threadIdx.x >> 6, lane = threadIdx.x & 63;
    long t = blockIdx.x * 4 + w;
    const float* xr = in + t * CC;
    float vals[12];
    float s = 0.f, sq = 0.f;
    #pragma unroll
    for (int i = 0; i < 3; i++) {
        int off = lane * 4 + i * 256;
        f32x4 v4 = *(const f32x4*)&xr[off];
        #pragma unroll
        for (int e = 0; e < 4; e++) {
            vals[i * 4 + e] = v4[e];
            s += v4[e]; sq += v4[e] * v4[e];
        }
    }
    #pragma unroll
    for (int m = 1; m < 64; m <<= 1) { s += __shfl_xor(s, m); sq += __shfl_xor(sq, m); }
    float mean = s * (1.f / 768.f);
    float var  = sq * (1.f / 768.f) - mean * mean;
    float rstd = rsqrtf(var + 1e-5f);
    bf16* orow = out + t * CC;
    #pragma unroll
    for (int i = 0; i < 3; i++) {
        int off = lane * 4 + i * 256;
        bf16x4 ov;
        #pragma unroll
        for (int e = 0; e < 4; e++)
            ov[e] = (bf16)((vals[i * 4 + e] - mean) * rstd * g[off + e] + bt[off + e]);
        *(bf16x4*)&orow[off] = ov;
    }
}

// ---------------- LN2 unified (both halves) + x1 += g2*fc2_bias writeback ----------------
__global__ __launch_bounds__(256) void ln2_kernel(
    float* x1, bf16* __restrict__ h2,
    const float* __restrict__ gt, const float* __restrict__ btt,
    const float* __restrict__ gf, const float* __restrict__ btf,
    const float* __restrict__ g2, const float* __restrict__ b2t, const float* __restrict__ b2f)
{
    int w = threadIdx.x >> 6, lane = threadIdx.x & 63;
    long u = blockIdx.x * 4 + w;      // token 0..8191
    int b = (int)(u >> 9), n = (int)(u & 511);
    bool th = n < 256;
    const float* g  = th ? gt : gf;
    const float* bt = th ? btt : btf;
    const float* b2 = th ? b2t : b2f;
    long h2row = th ? ((long)b * 256 + n) : (4096 + (long)b * 256 + (n - 256));
    float* xr = x1 + u * CC;
    float vals[12];
    float s = 0.f, sq = 0.f;
    #pragma unroll
    for (int i = 0; i < 3; i++) {
        int off = lane * 4 + i * 256;
        f32x4 v4 = *(const f32x4*)&xr[off];
        #pragma unroll
        for (int e = 0; e < 4; e++) {
            vals[i * 4 + e] = v4[e];
            s += v4[e]; sq += v4[e] * v4[e];
        }
    }
    #pragma unroll
    for (int m = 1; m < 64; m <<= 1) { s += __shfl_xor(s, m); sq += __shfl_xor(sq, m); }
    float mean = s * (1.f / 768.f);
    float var  = sq * (1.f / 768.f) - mean * mean;
    float rstd = rsqrtf(var + 1e-5f);
    bf16* orow = h2 + h2row * CC;
    #pragma unroll
    for (int i = 0; i < 3; i++) {
        int off = lane * 4 + i * 256;
        bf16x4 ov;
        f32x4 wv;
        #pragma unroll
        for (int e = 0; e < 4; e++) {
            ov[e] = (bf16)((vals[i * 4 + e] - mean) * rstd * g[off + e] + bt[off + e]);
            wv[e] = vals[i * 4 + e] + g2[off + e] * b2[off + e];
        }
        *(bf16x4*)&orow[off] = ov;
        *(f32x4*)&xr[off] = wv;
    }
}

// ---------------- bias precompute: bb[h][i][j] = table[rpi[i*512+j]*12 + h] ----------------
__global__ __launch_bounds__(256) void bias_kernel(
    const int* __restrict__ rpi, const float* __restrict__ table, bf16* __restrict__ bb)
{
    int idx = blockIdx.x * 256 + threadIdx.x;
    int r = rpi[idx];
    #pragma unroll
    for (int h = 0; h < HH; h++) bb[h * (NN * NN) + idx] = (bf16)table[r * HH + h];
}

// ------- 128x128 MFMA GEMM, double-buffered, bf16 B via g2l16: C = A @ Bt^T -------
enum { MODE_QKV = 0, MODE_PROJ = 1, MODE_GELU = 2, MODE_OUT = 3 };

template<int MODE, int K, int KCHUNK>
__global__ __launch_bounds__(256) void gemm_bt(
    const bf16* __restrict__ A, const bf16* __restrict__ Btb,
    const float* __restrict__ cbias, const float* residf,
    const float* __restrict__ gamma,
    bf16* __restrict__ outb0, bf16* __restrict__ outb1, bf16* __restrict__ outb2,
    float* outf, int rowbase)
{
    __shared__ bf16 lsA[2][128 * 32];
    __shared__ bf16 lsB[2][128 * 32];
    int tid = threadIdx.x;
    int lane = tid & 63, w = tid >> 6;
    int wm = w & 1, wn = w >> 1;
    long m0 = (long)blockIdx.y * 128;
    long n0 = (long)blockIdx.x * 128;
    long kb = (long)blockIdx.z * KCHUNK;
    f32x4 acc[4][4] = {};
    const bf16* Ab = A + m0 * K + kb;
    const bf16* Bb = Btb + n0 * K + kb;
    int r0 = tid >> 2, kg0 = (tid & 3) * 8;   // 8 bf16 = 16B per lane
    int la = lane & 15, hk = (lane >> 4) * 8;

    // prologue: stage k0=0 into buffer 0
    g2l16(Ab + (long)r0 * K + kg0,        lsA[0] + tid * 8);
    g2l16(Ab + (long)(r0 + 64) * K + kg0, lsA[0] + (tid + 256) * 8);
    g2l16(Bb + (long)r0 * K + kg0,        lsB[0] + tid * 8);
    g2l16(Bb + (long)(r0 + 64) * K + kg0, lsB[0] + (tid + 256) * 8);
    __syncthreads();

    int p = 0;
    for (int k0 = 0; k0 < KCHUNK; k0 += 32) {
        if (k0 + 32 < KCHUNK) {
            g2l16(Ab + (long)r0 * K + (k0 + 32) + kg0,        lsA[p ^ 1] + tid * 8);
            g2l16(Ab + (long)(r0 + 64) * K + (k0 + 32) + kg0, lsA[p ^ 1] + (tid + 256) * 8);
            g2l16(Bb + (long)r0 * K + (k0 + 32) + kg0,        lsB[p ^ 1] + tid * 8);
            g2l16(Bb + (long)(r0 + 64) * K + (k0 + 32) + kg0, lsB[p ^ 1] + (tid + 256) * 8);
        }
        bf16x8 af[4], bfr[4];
        #pragma unroll
        for (int mi = 0; mi < 4; mi++) af[mi]  = *(bf16x8*)&lsA[p][(wm * 64 + mi * 16 + la) * 32 + hk];
        #pragma unroll
        for (int ni = 0; ni < 4; ni++) bfr[ni] = *(bf16x8*)&lsB[p][(wn * 64 + ni * 16 + la) * 32 + hk];
        #pragma unroll
        for (int mi = 0; mi < 4; mi++)
            #pragma unroll
            for (int ni = 0; ni < 4; ni++)
                acc[mi][ni] = mfma16(af[mi], bfr[ni], acc[mi][ni]);
        __syncthreads();
        p ^= 1;
    }

    int q4 = (lane >> 4) * 4;
    #pragma unroll
    for (int mi = 0; mi < 4; mi++) {
        #pragma unroll
        for (int ni = 0; ni < 4; ni++) {
            long rb = m0 + wm * 64 + mi * 16 + q4;
            long c  = n0 + wn * 64 + ni * 16 + la;
            #pragma unroll
            for (int i = 0; i < 4; i++) {
                long r = rb + i;
                float v = acc[mi][ni][i];
                if (MODE == MODE_QKV) {
                    int oc = (int)c;
                    int s = oc / CC, rem = oc % CC;
                    int hh = rem >> 6, d = rem & 63;
                    long b = r >> 9, n = r & 511;
                    long dst = (((b * HH + hh) << 9) + n) * 64 + d;
                    if (s == 0)      outb0[dst] = (bf16)(v * 0.125f);
                    else if (s == 1) outb1[dst] = (bf16)v;
                    else             outb2[dst] = (bf16)v;
                } else if (MODE == MODE_PROJ) {
                    float val = v + cbias[c];
                    long idx = r * CC + c;
                    outf[idx] = residf[idx] + gamma[c] * val;
                } else if (MODE == MODE_GELU) {
                    float val = v + cbias[c];
                    float gl = 0.5f * val * (1.f + erff(val * 0.70710678118f));
                    outb0[r * (long)HID + c] = (bf16)gl;
                } else {  // MODE_OUT: bias pre-added by ln2 writeback; split-K atomic accumulate
                    long grow = (r >> 8) * NN + (r & 255) + rowbase;
                    atomicAdd(outf + grow * CC + c, gamma[c] * v);
                }
            }
        }
    }
}

// ---------------- Flash attention: block = (h, qt, b), b fastest for bias L2 reuse ----------------
// 64-col K-chunks. lsK stride 72, lsVT stride 68 (uniform both ways), lsP stride 76.
__global__ __launch_bounds__(256) void attn_kernel(
    const bf16* __restrict__ q, const bf16* __restrict__ k, const bf16* __restrict__ v,
    const bf16* __restrict__ bb, bf16* __restrict__ o)
{
    __shared__ bf16 lsK[64 * 72];
    __shared__ bf16 lsVT[64 * 68];
    __shared__ bf16 lsP[4][16 * 76];
    int tid = threadIdx.x, lane = tid & 63, w = tid >> 6;
    int b  = blockIdx.x & 15;
    int qt = (blockIdx.x >> 4) & 7;
    int h  = blockIdx.x >> 7;
    long base = (long)(b * HH + h) * NN * DD;
    int la = lane & 15, hi = lane >> 4;
    int qr0 = qt * 64 + w * 16;
    const bf16* brow = bb + (long)h * NN * NN;

    bf16x8 qf0 = *(const bf16x8*)&q[base + (qr0 + la) * 64 + hi * 8];
    bf16x8 qf1 = *(const bf16x8*)&q[base + (qr0 + la) * 64 + 32 + hi * 8];
    f32x4 of[4] = {};
    float m[4], l[4];
    #pragma unroll
    for (int i = 0; i < 4; i++) { m[i] = -1e30f; l[i] = 0.f; }

    int jr = tid >> 2, dg16 = (tid & 3) * 16;
    for (int ch = 0; ch < 8; ch++) {
        int j0 = ch * 64;
        const bf16* krow = &k[base + (long)(j0 + jr) * 64 + dg16];
        *(bf16x8*)&lsK[jr * 72 + dg16]     = *(const bf16x8*)krow;
        *(bf16x8*)&lsK[jr * 72 + dg16 + 8] = *(const bf16x8*)(krow + 8);
        const bf16* vrow = &v[base + (long)(j0 + jr) * 64 + dg16];
        bf16x8 v0 = *(const bf16x8*)vrow;
        bf16x8 v1 = *(const bf16x8*)(vrow + 8);
        #pragma unroll
        for (int e = 0; e < 8; e++) {
            lsVT[(dg16 + e) * 68 + jr]     = v0[e];
            lsVT[(dg16 + 8 + e) * 68 + jr] = v1[e];
        }
        __syncthreads();

        f32x4 s[4] = {};
        #pragma unroll
        for (int t = 0; t < 4; t++) {
            bf16x8 kf0 = *(bf16x8*)&lsK[(t * 16 + la) * 72 + hi * 8];
            bf16x8 kf1 = *(bf16x8*)&lsK[(t * 16 + la) * 72 + 32 + hi * 8];
            s[t] = mfma16(qf0, kf0, s[t]);
            s[t] = mfma16(qf1, kf1, s[t]);
        }
        // + relative position bias
        #pragma unroll
        for (int i = 0; i < 4; i++) {
            long bi = (long)(qr0 + hi * 4 + i) * NN + j0 + la;
            s[0][i] += (float)brow[bi];
            s[1][i] += (float)brow[bi + 16];
            s[2][i] += (float)brow[bi + 32];
            s[3][i] += (float)brow[bi + 48];
        }
        // online softmax over 64 cols (rows live in 16-lane groups)
        float alpha[4];
        #pragma unroll
        for (int i = 0; i < 4; i++) {
            float mx = fmaxf(fmaxf(s[0][i], s[1][i]), fmaxf(s[2][i], s[3][i]));
            #pragma unroll
            for (int msk = 1; msk < 16; msk <<= 1) mx = fmaxf(mx, __shfl_xor(mx, msk));
            float mn = fmaxf(m[i], mx);
            alpha[i] = __expf(m[i] - mn);
            m[i] = mn;
            float rs = 0.f;
            #pragma unroll
            for (int t = 0; t < 4; t++) { s[t][i] = __expf(s[t][i] - mn); rs += s[t][i]; }
            #pragma unroll
            for (int msk = 1; msk < 16; msk <<= 1) rs += __shfl_xor(rs, msk);
            l[i] = l[i] * alpha[i] + rs;
        }
        #pragma unroll
        for (int t = 0; t < 4; t++)
            #pragma unroll
            for (int i = 0; i < 4; i++) of[t][i] *= alpha[i];
        // P: C-layout -> A-layout via wave-private LDS
        #pragma unroll
        for (int i = 0; i < 4; i++) {
            #pragma unroll
            for (int t = 0; t < 4; t++)
                lsP[w][(hi * 4 + i) * 76 + t * 16 + la] = (bf16)s[t][i];
        }
        __syncthreads();
        bf16x8 pf0 = *(bf16x8*)&lsP[w][la * 76 + hi * 8];
        bf16x8 pf1 = *(bf16x8*)&lsP[w][la * 76 + 32 + hi * 8];
        #pragma unroll
        for (int t = 0; t < 4; t++) {
            bf16x8 vf0 = *(bf16x8*)&lsVT[(t * 16 + la) * 68 + hi * 8];
            bf16x8 vf1 = *(bf16x8*)&lsVT[(t * 16 + la) * 68 + 32 + hi * 8];
            of[t] = mfma16(pf0, vf0, of[t]);
            of[t] = mfma16(pf1, vf1, of[t]);
        }
        __syncthreads();
    }
    #pragma unroll
    for (int t = 0; t < 4; t++) {
        #pragma unroll
        for (int i = 0; i < 4; i++) {
            long row = (long)b * NN + qr0 + hi * 4 + i;
            o[row * CC + h * 64 + t * 16 + la] = (bf16)(of[t][i] / l[i]);
        }
    }
}

extern "C" void kernel_launch(void* const* d_in, const int* in_sizes, int n_in,
                              void* d_out, int out_size, void* d_ws, size_t ws_size,
                              hipStream_t stream)
{
    const float* x     = (const float*)d_in[0];
    const int*   rpi   = (const int*)d_in[2];
    const float* Wqkv  = (const float*)d_in[3];
    const float* Wproj = (const float*)d_in[4];
    const float* bproj = (const float*)d_in[5];
    const float* rtab  = (const float*)d_in[6];
    const float* ln1g  = (const float*)d_in[7];
    const float* ln1b  = (const float*)d_in[8];
    const float* g1    = (const float*)d_in[9];
    const float* g2    = (const float*)d_in[10];
    const float* ln2tg = (const float*)d_in[11];
    const float* ln2tb = (const float*)d_in[12];
    const float* f1tW  = (const float*)d_in[13];
    const float* f1tb  = (const float*)d_in[14];
    const float* f2tW  = (const float*)d_in[15];
    const float* f2tb  = (const float*)d_in[16];
    const float* ln2fg = (const float*)d_in[17];
    const float* ln2fb = (const float*)d_in[18];
    const float* f1fW  = (const float*)d_in[19];
    const float* f1fb  = (const float*)d_in[20];
    const float* f2fW  = (const float*)d_in[21];
    const float* f2fb  = (const float*)d_in[22];
    float* out = (float*)d_out;

    // ws: 4 regions x 12.58MB bf16 = 50.33MB.
    //  rA: q  -> Wproj(bf16) -> h2        rB: k -> hg lo     rC: v -> hg hi
    //  rD: Wqkv(bf16) -> o -> MLP weight pairs (w1,w2 bf16)
    // d_out: h (bf16 LN1) -> bias table (bf16) -> x1 (fp32 residual/result)
    char* ws = (char*)d_ws;
    const long TOKC = (long)BB * NN * CC;        // 6291456
    const int  NFC  = HID * CC;                  // 2359296
    bf16* rA = (bf16*)ws;
    bf16* rB = rA + TOKC;
    bf16* rC = rB + TOKC;
    bf16* rD = rC + TOKC;

    bf16 *qb = rA, *kb = rB, *vb = rC, *o = rD;
    bf16  *h    = (bf16*)d_out;
    bf16  *bbt  = (bf16*)d_out;
    float *x1   = out;
    bf16  *wqkv = rD;     // before o
    bf16  *wpro = rA;     // after q dies
    bf16  *h2   = rA;     // after Wproj dies
    bf16  *hg   = rB;     // spans rB+rC
    bf16  *w1   = rD;     // after o dies
    bf16  *w2   = rD + NFC;

    // 0a. cast Wqkv -> bf16 (rD; o not yet written)
    cast2_kernel<<<1728, 256, 0, stream>>>(Wqkv, 442368, nullptr, wqkv);
    // 1. LN1: fp32 x -> bf16 h (d_out)
    ln_kernel<<<2048, 256, 0, stream>>>(x, h, ln1g, ln1b);
    // 2. QKV projection
    {
        dim3 g(2304 / 128, 8192 / 128, 1);
        gemm_bt<MODE_QKV, 768, 768><<<g, 256, 0, stream>>>(h, wqkv, nullptr, nullptr, nullptr, qb, kb, vb, nullptr, 0);
    }
    // 3. bias table (h dead)
    bias_kernel<<<1024, 256, 0, stream>>>(rpi, rtab, bbt);
    // 4. attention (reads rA,rB,rC,bbt; writes o=rD; wqkv dead)
    attn_kernel<<<BB * HH * 8, 256, 0, stream>>>(qb, kb, vb, bbt, o);
    // 5a. cast Wproj -> bf16 (rA; q dead)
    cast2_kernel<<<576, 256, 0, stream>>>(Wproj, 147456, nullptr, wpro);
    // 5b. proj + residual -> x1 (overwrites d_out; bbt dead)
    {
        dim3 g(768 / 128, 8192 / 128, 1);
        gemm_bt<MODE_PROJ, 768, 768><<<g, 256, 0, stream>>>(o, wpro, bproj, x, g1, nullptr, nullptr, nullptr, x1, 0);
    }
    // 6. LN2 both halves -> h2 (rA; Wproj dead), x1 += g2*fc2_bias
    ln2_kernel<<<2048, 256, 0, stream>>>(x1, h2, ln2tg, ln2tb, ln2fg, ln2fb, g2, f2tb, f2fb);
    // 7. MLP t-half: cast weights (rD; o dead), GELU, OUT split-K=4
    cast2_kernel<<<4608, 256, 0, stream>>>(f1tW, NFC / 4, f2tW, w1);
    {
        dim3 ga(3072 / 128, 4096 / 128, 1);
        gemm_bt<MODE_GELU, 768, 768><<<ga, 256, 0, stream>>>(h2, w1, f1tb, nullptr, nullptr, hg, nullptr, nullptr, nullptr, 0);
        dim3 gb(768 / 128, 4096 / 128, 4);
        gemm_bt<MODE_OUT, 3072, 768><<<gb, 256, 0, stream>>>(hg, w2, nullptr, nullptr, g2, nullptr, nullptr, nullptr, out, 0);
    }
    // 8. MLP f-half
    cast2_kernel<<<4608, 256, 0, stream>>>(f1fW, NFC / 4, f2fW, w1);
    {
        dim3 ga(3072 / 128, 4096 / 128, 1);
        gemm_bt<MODE_GELU, 768, 768><<<ga, 256, 0, stream>>>(h2 + (long)4096 * CC, w1, f1fb, nullptr, nullptr, hg, nullptr, nullptr, nullptr, 0);
        dim3 gb(768 / 128, 4096 / 128, 4);
        gemm_bt<MODE_OUT, 3072, 768><<<gb, 256, 0, stream>>>(hg, w2, nullptr, nullptr, g2, nullptr, nullptr, nullptr, out, 256);
    }
}